// Round 16
// baseline (119.399 us; speedup 1.0000x reference)
//
#include <hip/hip_runtime.h>

#define D 64
#define ROWS 64
#define TPB 256

typedef float f4 __attribute__((ext_vector_type(4)));
typedef short s8 __attribute__((ext_vector_type(8)));

static __device__ __forceinline__ unsigned short f2bf(float x) {
  union { float f; unsigned u; } v; v.f = x;
  return (unsigned short)((v.u + 0x7FFFu + ((v.u >> 16) & 1u)) >> 16);
}

static __device__ __forceinline__ s8 pack8(f4 a, f4 b) {
  s8 r;
  r[0] = (short)f2bf(a.x); r[1] = (short)f2bf(a.y);
  r[2] = (short)f2bf(a.z); r[3] = (short)f2bf(a.w);
  r[4] = (short)f2bf(b.x); r[5] = (short)f2bf(b.y);
  r[6] = (short)f2bf(b.z); r[7] = (short)f2bf(b.w);
  return r;
}

static __device__ __forceinline__ f4 fma4s(float a, f4 b, f4 c) {
  f4 r;
  r.x = fmaf(a, b.x, c.x);
  r.y = fmaf(a, b.y, c.y);
  r.z = fmaf(a, b.z, c.z);
  r.w = fmaf(a, b.w, c.w);
  return r;
}

static __device__ __forceinline__ f4 prelu4(f4 p, float a) {
  f4 r;
  r.x = p.x >= 0.0f ? p.x : a * p.x;
  r.y = p.y >= 0.0f ? p.y : a * p.y;
  r.z = p.z >= 0.0f ? p.z : a * p.z;
  r.w = p.w >= 0.0f ? p.w : a * p.w;
  return r;
}

static __device__ __forceinline__ float dot4(f4 x, f4 y, f4 z, float acc) {
  acc = fmaf(x.x + y.x, z.x, acc);
  acc = fmaf(x.y + y.y, z.y, acc);
  acc = fmaf(x.z + y.z, z.z, acc);
  acc = fmaf(x.w + y.w, z.w, acc);
  return acc;
}

// Consume one tile: gate + pack + MFMA + gated residual + norm + store.
// All operands in registers / LDS; fully inlined.
static __device__ __forceinline__ void consume_tile(
    const int j0, const int nrem, const int r, const int g, const int rl,
    const f4 ph0a, const f4 ph0b, const f4 ph1a, const f4 ph1b,
    const f4 pk0a, const f4 pk0b, const f4 pk1a, const f4 pk1b,
    const f4 hr0, const f4 hr1, const f4 hr2, const f4 hr3,
    const f4 sA0, const f4 sA1, const f4 sB0, const f4 sB1,
    const s8* __restrict__ Ub8, const s8* __restrict__ Vb8,
    const f4* __restrict__ cc4, const float a,
    float* __restrict__ out) {
  float gd = dot4(ph0a, pk0a, sA0, 0.0f);
  gd = dot4(ph0b, pk0b, sA1, gd);
  gd = dot4(ph1a, pk1a, sB0, gd);
  gd = dot4(ph1b, pk1b, sB1, gd);
  const s8 bh0 = pack8(ph0a, ph0b);
  const s8 bh1 = pack8(ph1a, ph1b);
  const s8 bk0 = pack8(pk0a, pk0b);
  const s8 bk1 = pack8(pk1a, pk1b);

  f4 acc0 = cc4[0 + g];
  f4 acc1 = cc4[4 + g];
  f4 acc2 = cc4[8 + g];
  f4 acc3 = cc4[12 + g];

  #pragma unroll
  for (int ks = 0; ks < 2; ++ks) {
    const int asl = ks * 4 + g;
    const s8 bh = (ks == 0) ? bh0 : bh1;
    const s8 bk = (ks == 0) ? bk0 : bk1;
    const int c0i = 0 * 16 + rl, c1i = 1 * 16 + rl;
    const int c2i = 2 * 16 + rl, c3i = 3 * 16 + rl;
    const s8 au0 = Ub8[c0i * 8 + (asl ^ (c0i & 7))];
    const s8 au1 = Ub8[c1i * 8 + (asl ^ (c1i & 7))];
    const s8 au2 = Ub8[c2i * 8 + (asl ^ (c2i & 7))];
    const s8 au3 = Ub8[c3i * 8 + (asl ^ (c3i & 7))];
    const s8 av0 = Vb8[c0i * 8 + (asl ^ (c0i & 7))];
    const s8 av1 = Vb8[c1i * 8 + (asl ^ (c1i & 7))];
    const s8 av2 = Vb8[c2i * 8 + (asl ^ (c2i & 7))];
    const s8 av3 = Vb8[c3i * 8 + (asl ^ (c3i & 7))];
    acc0 = __builtin_amdgcn_mfma_f32_16x16x32_bf16(au0, bh, acc0, 0, 0, 0);
    acc1 = __builtin_amdgcn_mfma_f32_16x16x32_bf16(au1, bh, acc1, 0, 0, 0);
    acc2 = __builtin_amdgcn_mfma_f32_16x16x32_bf16(au2, bh, acc2, 0, 0, 0);
    acc3 = __builtin_amdgcn_mfma_f32_16x16x32_bf16(au3, bh, acc3, 0, 0, 0);
    acc0 = __builtin_amdgcn_mfma_f32_16x16x32_bf16(av0, bk, acc0, 0, 0, 0);
    acc1 = __builtin_amdgcn_mfma_f32_16x16x32_bf16(av1, bk, acc1, 0, 0, 0);
    acc2 = __builtin_amdgcn_mfma_f32_16x16x32_bf16(av2, bk, acc2, 0, 0, 0);
    acc3 = __builtin_amdgcn_mfma_f32_16x16x32_bf16(av3, bk, acc3, 0, 0, 0);
  }

  gd += __shfl_xor(gd, 16);
  gd += __shfl_xor(gd, 32);
  const float gt = 1.0f / (1.0f + __expf(-gd));

  f4 o0 = fma4s(gt, prelu4(acc0, a), hr0);
  f4 o1 = fma4s(gt, prelu4(acc1, a), hr1);
  f4 o2 = fma4s(gt, prelu4(acc2, a), hr2);
  f4 o3 = fma4s(gt, prelu4(acc3, a), hr3);

  float ss = o0.x * o0.x + o0.y * o0.y + o0.z * o0.z + o0.w * o0.w;
  ss = fmaf(o1.x, o1.x, ss); ss = fmaf(o1.y, o1.y, ss);
  ss = fmaf(o1.z, o1.z, ss); ss = fmaf(o1.w, o1.w, ss);
  ss = fmaf(o2.x, o2.x, ss); ss = fmaf(o2.y, o2.y, ss);
  ss = fmaf(o2.z, o2.z, ss); ss = fmaf(o2.w, o2.w, ss);
  ss = fmaf(o3.x, o3.x, ss); ss = fmaf(o3.y, o3.y, ss);
  ss = fmaf(o3.z, o3.z, ss); ss = fmaf(o3.w, o3.w, ss);
  ss += __shfl_xor(ss, 16);
  ss += __shfl_xor(ss, 32);
  const float rn = rsqrtf(ss);

  if (r < nrem) {
    float* __restrict__ orow = out + (size_t)(j0 + r) * D + g * 4;
    *reinterpret_cast<f4*>(orow +  0) = o0 * rn;
    *reinterpret_cast<f4*>(orow + 16) = o1 * rn;
    *reinterpret_cast<f4*>(orow + 32) = o2 * rn;
    *reinterpret_cast<f4*>(orow + 48) = o3 * rn;
  }
}

// R16: two CONTIGUOUS tiles per block (grid 3907, dispatch order preserved ->
// keeps R10/R15's ~50% L3 hit). BOTH tiles' 12-f4 load bundles issue up
// front (straight-line, no loop-carry -> no R12 demotion), pinned by
// sched_barrier; U/V/cc staging overlaps them; consume A then B. Loads stay
// outstanding across staging AND A-compute (R15's duty-cycle limiter), and
// per-block U/V/W staging traffic halves.
__global__ __launch_bounds__(TPB, 3) void dmc_fused(
    const float* __restrict__ h,
    const float* __restrict__ keys,
    const float* __restrict__ s,
    const float* __restrict__ U,
    const float* __restrict__ V,
    const float* __restrict__ W,
    const float* __restrict__ bias,
    const float* __restrict__ prelu_a,
    float* __restrict__ out,
    const int nblocks,
    const int ntiles) {
  __shared__ __align__(16) unsigned short Ub[D * D];  // 8KB bf16, swizzled
  __shared__ __align__(16) unsigned short Vb[D * D];  // 8KB
  __shared__ __align__(16) float cc[D];

  const int tid  = threadIdx.x;
  const int lane = tid & 63;
  const int wv   = tid >> 6;
  const int g    = lane >> 4;
  const int rl   = lane & 15;
  const int r    = wv * 16 + rl;

  const int tA = blockIdx.x * 2;
  const int tB = tA + 1;
  const bool hasB = (tB < ntiles);

  // ---- 1) issue tile A's 12 loads, then tile B's 12 loads ----
  const int j0A = tA * ROWS;
  const int nremA = nblocks - j0A;
  const int rcA = (r < nremA) ? r : (nremA - 1);
  const f4* __restrict__ hrA = reinterpret_cast<const f4*>(h + (size_t)(j0A + rcA) * D);
  const f4* __restrict__ krA = reinterpret_cast<const f4*>(keys + (size_t)(j0A + rcA) * D);
  const f4 Ah0a = hrA[2 * g];      const f4 Ah0b = hrA[2 * g + 1];
  const f4 Ah1a = hrA[8 + 2 * g];  const f4 Ah1b = hrA[8 + 2 * g + 1];
  const f4 Ak0a = krA[2 * g];      const f4 Ak0b = krA[2 * g + 1];
  const f4 Ak1a = krA[8 + 2 * g];  const f4 Ak1b = krA[8 + 2 * g + 1];
  const f4 Ar0 = hrA[0 + g];
  const f4 Ar1 = hrA[4 + g];
  const f4 Ar2 = hrA[8 + g];
  const f4 Ar3 = hrA[12 + g];

  f4 Bh0a = {0,0,0,0}, Bh0b = Bh0a, Bh1a = Bh0a, Bh1b = Bh0a;
  f4 Bk0a = Bh0a, Bk0b = Bh0a, Bk1a = Bh0a, Bk1b = Bh0a;
  f4 Br0 = Bh0a, Br1 = Bh0a, Br2 = Bh0a, Br3 = Bh0a;
  int j0B = 0, nremB = 0;
  if (hasB) {
    j0B = tB * ROWS;
    nremB = nblocks - j0B;
    const int rcB = (r < nremB) ? r : (nremB - 1);
    const f4* __restrict__ hrB = reinterpret_cast<const f4*>(h + (size_t)(j0B + rcB) * D);
    const f4* __restrict__ krB = reinterpret_cast<const f4*>(keys + (size_t)(j0B + rcB) * D);
    Bh0a = hrB[2 * g];      Bh0b = hrB[2 * g + 1];
    Bh1a = hrB[8 + 2 * g];  Bh1b = hrB[8 + 2 * g + 1];
    Bk0a = krB[2 * g];      Bk0b = krB[2 * g + 1];
    Bk1a = krB[8 + 2 * g];  Bk1b = krB[8 + 2 * g + 1];
    Br0 = hrB[0 + g];
    Br1 = hrB[4 + g];
    Br2 = hrB[8 + g];
    Br3 = hrB[12 + g];
  }
  // Pin: staging below must not be hoisted above these loads.
  __builtin_amdgcn_sched_barrier(0);

  // ---- 2) stage U, V -> bf16 LDS (overlaps the 24 in-flight loads) ----
  const f4* __restrict__ Ug = reinterpret_cast<const f4*>(U);
  const f4* __restrict__ Vg = reinterpret_cast<const f4*>(V);
  s8* __restrict__ Ub8w = reinterpret_cast<s8*>(Ub);
  s8* __restrict__ Vb8w = reinterpret_cast<s8*>(Vb);
  #pragma unroll
  for (int t = 0; t < 2; ++t) {
    const int m  = tid + TPB * t;
    const int c  = m >> 3;
    const int sl = m & 7;
    Ub8w[c * 8 + (sl ^ (c & 7))] = pack8(Ug[c * 16 + sl * 2], Ug[c * 16 + sl * 2 + 1]);
    Vb8w[c * 8 + (sl ^ (c & 7))] = pack8(Vg[c * 16 + sl * 2], Vg[c * 16 + sl * 2 + 1]);
  }

  // ---- cc[c] = bias[c] + W[c,:] @ s ----
  if (tid < D) {
    const f4* __restrict__ wr = reinterpret_cast<const f4*>(W + tid * D);
    const f4* __restrict__ sr = reinterpret_cast<const f4*>(s);
    float acc = bias[tid];
    #pragma unroll
    for (int q = 0; q < 16; ++q) {
      const f4 wq = wr[q];
      const f4 sq = sr[q];
      acc = fmaf(wq.x, sq.x, acc);
      acc = fmaf(wq.y, sq.y, acc);
      acc = fmaf(wq.z, sq.z, acc);
      acc = fmaf(wq.w, sq.w, acc);
    }
    cc[tid] = acc;
  }
  __syncthreads();

  // ---- hoisted uniforms ----
  const f4* __restrict__ sg4 = reinterpret_cast<const f4*>(s);
  const f4 sA0 = sg4[2 * g];
  const f4 sA1 = sg4[2 * g + 1];
  const f4 sB0 = sg4[8 + 2 * g];
  const f4 sB1 = sg4[8 + 2 * g + 1];
  const float a = prelu_a[0];
  const s8* __restrict__ Ub8 = reinterpret_cast<const s8*>(Ub);
  const s8* __restrict__ Vb8 = reinterpret_cast<const s8*>(Vb);
  const f4* __restrict__ cc4 = reinterpret_cast<const f4*>(cc);

  // ---- 3) consume A, then B (B's loads were outstanding through A) ----
  consume_tile(j0A, nremA, r, g, rl,
               Ah0a, Ah0b, Ah1a, Ah1b, Ak0a, Ak0b, Ak1a, Ak1b,
               Ar0, Ar1, Ar2, Ar3, sA0, sA1, sB0, sB1,
               Ub8, Vb8, cc4, a, out);
  if (hasB) {
    consume_tile(j0B, nremB, r, g, rl,
                 Bh0a, Bh0b, Bh1a, Bh1b, Bk0a, Bk0b, Bk1a, Bk1b,
                 Br0, Br1, Br2, Br3, sA0, sA1, sB0, sB1,
                 Ub8, Vb8, cc4, a, out);
  }
}

extern "C" void kernel_launch(void* const* d_in, const int* in_sizes, int n_in,
                              void* d_out, int out_size, void* d_ws, size_t ws_size,
                              hipStream_t stream) {
  const float* s       = (const float*)d_in[0];
  const float* h       = (const float*)d_in[1];
  const float* keys    = (const float*)d_in[2];
  const float* U       = (const float*)d_in[3];
  const float* V       = (const float*)d_in[4];
  const float* W       = (const float*)d_in[5];
  const float* bias    = (const float*)d_in[6];
  const float* prelu_a = (const float*)d_in[7];
  float* out = (float*)d_out;

  const int nblocks = in_sizes[1] / D;
  const int ntiles  = (nblocks + ROWS - 1) / ROWS;
  const int grid    = (ntiles + 1) / 2;
  dmc_fused<<<grid, TPB, 0, stream>>>(h, keys, s, U, V, W, bias, prelu_a, out,
                                      nblocks, ntiles);
}

// Round 17
// 106.848 us; speedup vs baseline: 1.1175x; 1.1175x over previous
//
#include <hip/hip_runtime.h>

#define D 64
#define ROWS 64
#define TPB 512

typedef float f4 __attribute__((ext_vector_type(4)));
typedef short s8 __attribute__((ext_vector_type(8)));

static __device__ __forceinline__ unsigned short f2bf(float x) {
  union { float f; unsigned u; } v; v.f = x;
  return (unsigned short)((v.u + 0x7FFFu + ((v.u >> 16) & 1u)) >> 16);
}

static __device__ __forceinline__ s8 pack8(f4 a, f4 b) {
  s8 r;
  r[0] = (short)f2bf(a.x); r[1] = (short)f2bf(a.y);
  r[2] = (short)f2bf(a.z); r[3] = (short)f2bf(a.w);
  r[4] = (short)f2bf(b.x); r[5] = (short)f2bf(b.y);
  r[6] = (short)f2bf(b.z); r[7] = (short)f2bf(b.w);
  return r;
}

static __device__ __forceinline__ f4 fma4s(float a, f4 b, f4 c) {
  f4 r;
  r.x = fmaf(a, b.x, c.x);
  r.y = fmaf(a, b.y, c.y);
  r.z = fmaf(a, b.z, c.z);
  r.w = fmaf(a, b.w, c.w);
  return r;
}

static __device__ __forceinline__ f4 prelu4(f4 p, float a) {
  f4 r;
  r.x = p.x >= 0.0f ? p.x : a * p.x;
  r.y = p.y >= 0.0f ? p.y : a * p.y;
  r.z = p.z >= 0.0f ? p.z : a * p.z;
  r.w = p.w >= 0.0f ? p.w : a * p.w;
  return r;
}

static __device__ __forceinline__ float dot4(f4 x, f4 y, f4 z, float acc) {
  acc = fmaf(x.x + y.x, z.x, acc);
  acc = fmaf(x.y + y.y, z.y, acc);
  acc = fmaf(x.z + y.z, z.z, acc);
  acc = fmaf(x.w + y.w, z.w, acc);
  return acc;
}

// R17 = R15's per-wave code with 512-thread blocks and WAVE-PRIVATE tiles.
// R16's 24-f4 cross-barrier bundle spilled (VGPR 84, WRITE 207MB); here each
// wave still holds only its OWN 12-f4 bundle (R15's proven 60-VGPR shape),
// but 8 waves/block cover 2 consecutive tiles (wave wv -> tile
// 2*blockIdx+(wv>>2), row-block wv&3). One U/V/cc staging + one barrier per
// 2 tiles (staging traffic halves); grid stays dispatch-ordered. R15's
// occupancy was 39% with nothing capping it at 60 VGPR/16.9KB LDS ->
// residency (avg outstanding bursts/CU) is the limiter; bigger blocks +
// launch_bounds(512,6) (cap 85, no spill risk) raise it.
__global__ __launch_bounds__(TPB, 6) void dmc_fused(
    const float* __restrict__ h,
    const float* __restrict__ keys,
    const float* __restrict__ s,
    const float* __restrict__ U,
    const float* __restrict__ V,
    const float* __restrict__ W,
    const float* __restrict__ bias,
    const float* __restrict__ prelu_a,
    float* __restrict__ out,
    const int nblocks,
    const int ntiles) {
  __shared__ __align__(16) unsigned short Ub[D * D];  // 8KB bf16, swizzled
  __shared__ __align__(16) unsigned short Vb[D * D];  // 8KB
  __shared__ __align__(16) float cc[D];

  const int tid  = threadIdx.x;
  const int lane = tid & 63;
  const int wv   = tid >> 6;            // 0..7
  const int g    = lane >> 4;           // 0..3
  const int rl   = lane & 15;           // MFMA n (batch row) / m (U row)
  const int wq   = wv & 3;              // row-block within the wave's tile
  const int r    = wq * 16 + rl;        // batch row within tile

  const int tile = blockIdx.x * 2 + (wv >> 2);
  const bool hasT = (tile < ntiles);
  const int j0   = hasT ? tile * ROWS : 0;
  const int nrem = nblocks - j0;
  const int rc   = (r < nrem) ? r : (nrem - 1);

  // ---- 1) issue this wave's 12 f4 loads first ----
  const f4* __restrict__ hrow = reinterpret_cast<const f4*>(h + (size_t)(j0 + rc) * D);
  const f4* __restrict__ krow = reinterpret_cast<const f4*>(keys + (size_t)(j0 + rc) * D);
  const f4 ph0a = hrow[2 * g];      const f4 ph0b = hrow[2 * g + 1];
  const f4 ph1a = hrow[8 + 2 * g];  const f4 ph1b = hrow[8 + 2 * g + 1];
  const f4 pk0a = krow[2 * g];      const f4 pk0b = krow[2 * g + 1];
  const f4 pk1a = krow[8 + 2 * g];  const f4 pk1b = krow[8 + 2 * g + 1];
  const f4 hr0 = hrow[0 + g];
  const f4 hr1 = hrow[4 + g];
  const f4 hr2 = hrow[8 + g];
  const f4 hr3 = hrow[12 + g];
  // Pin: staging below must not be hoisted above these loads.
  __builtin_amdgcn_sched_barrier(0);

  // ---- 2) stage U, V -> bf16 LDS (512 chunks, one per thread) ----
  const f4* __restrict__ Ug = reinterpret_cast<const f4*>(U);
  const f4* __restrict__ Vg = reinterpret_cast<const f4*>(V);
  s8* __restrict__ Ub8w = reinterpret_cast<s8*>(Ub);
  s8* __restrict__ Vb8w = reinterpret_cast<s8*>(Vb);
  {
    const int c  = tid >> 3;
    const int sl = tid & 7;
    Ub8w[c * 8 + (sl ^ (c & 7))] = pack8(Ug[c * 16 + sl * 2], Ug[c * 16 + sl * 2 + 1]);
    Vb8w[c * 8 + (sl ^ (c & 7))] = pack8(Vg[c * 16 + sl * 2], Vg[c * 16 + sl * 2 + 1]);
  }

  // ---- cc[c] = bias[c] + W[c,:] @ s ----
  if (tid < D) {
    const f4* __restrict__ wr = reinterpret_cast<const f4*>(W + tid * D);
    const f4* __restrict__ sr = reinterpret_cast<const f4*>(s);
    float acc = bias[tid];
    #pragma unroll
    for (int q = 0; q < 16; ++q) {
      const f4 wq4 = wr[q];
      const f4 sq = sr[q];
      acc = fmaf(wq4.x, sq.x, acc);
      acc = fmaf(wq4.y, sq.y, acc);
      acc = fmaf(wq4.z, sq.z, acc);
      acc = fmaf(wq4.w, sq.w, acc);
    }
    cc[tid] = acc;
  }
  __syncthreads();

  // ---- 3) consume: gate dot (f32, pre-pack) + B-frag packs ----
  const f4* __restrict__ sg4 = reinterpret_cast<const f4*>(s);
  float gd = dot4(ph0a, pk0a, sg4[2 * g], 0.0f);
  gd = dot4(ph0b, pk0b, sg4[2 * g + 1], gd);
  gd = dot4(ph1a, pk1a, sg4[8 + 2 * g], gd);
  gd = dot4(ph1b, pk1b, sg4[8 + 2 * g + 1], gd);
  const s8 bh0 = pack8(ph0a, ph0b);
  const s8 bh1 = pack8(ph1a, ph1b);
  const s8 bk0 = pack8(pk0a, pk0b);
  const s8 bk1 = pack8(pk1a, pk1b);

  // ---- accumulators from cc ----
  const f4* __restrict__ cc4 = reinterpret_cast<const f4*>(cc);
  f4 acc0 = cc4[0 + g];
  f4 acc1 = cc4[4 + g];
  f4 acc2 = cc4[8 + g];
  f4 acc3 = cc4[12 + g];

  // ---- MFMA: K=64 as 2 slices of 32 (A-frags from swizzled LDS) ----
  const s8* __restrict__ Ub8 = reinterpret_cast<const s8*>(Ub);
  const s8* __restrict__ Vb8 = reinterpret_cast<const s8*>(Vb);
  #pragma unroll
  for (int ks = 0; ks < 2; ++ks) {
    const int asl = ks * 4 + g;
    const s8 bh = (ks == 0) ? bh0 : bh1;
    const s8 bk = (ks == 0) ? bk0 : bk1;
    const int c0i = 0 * 16 + rl, c1i = 1 * 16 + rl;
    const int c2i = 2 * 16 + rl, c3i = 3 * 16 + rl;
    const s8 au0 = Ub8[c0i * 8 + (asl ^ (c0i & 7))];
    const s8 au1 = Ub8[c1i * 8 + (asl ^ (c1i & 7))];
    const s8 au2 = Ub8[c2i * 8 + (asl ^ (c2i & 7))];
    const s8 au3 = Ub8[c3i * 8 + (asl ^ (c3i & 7))];
    const s8 av0 = Vb8[c0i * 8 + (asl ^ (c0i & 7))];
    const s8 av1 = Vb8[c1i * 8 + (asl ^ (c1i & 7))];
    const s8 av2 = Vb8[c2i * 8 + (asl ^ (c2i & 7))];
    const s8 av3 = Vb8[c3i * 8 + (asl ^ (c3i & 7))];
    acc0 = __builtin_amdgcn_mfma_f32_16x16x32_bf16(au0, bh, acc0, 0, 0, 0);
    acc1 = __builtin_amdgcn_mfma_f32_16x16x32_bf16(au1, bh, acc1, 0, 0, 0);
    acc2 = __builtin_amdgcn_mfma_f32_16x16x32_bf16(au2, bh, acc2, 0, 0, 0);
    acc3 = __builtin_amdgcn_mfma_f32_16x16x32_bf16(au3, bh, acc3, 0, 0, 0);
    acc0 = __builtin_amdgcn_mfma_f32_16x16x32_bf16(av0, bk, acc0, 0, 0, 0);
    acc1 = __builtin_amdgcn_mfma_f32_16x16x32_bf16(av1, bk, acc1, 0, 0, 0);
    acc2 = __builtin_amdgcn_mfma_f32_16x16x32_bf16(av2, bk, acc2, 0, 0, 0);
    acc3 = __builtin_amdgcn_mfma_f32_16x16x32_bf16(av3, bk, acc3, 0, 0, 0);
  }

  // ---- gate reduce (lanes of equal rl hold disjoint k-ranges) ----
  gd += __shfl_xor(gd, 16);
  gd += __shfl_xor(gd, 32);
  const float gt = 1.0f / (1.0f + __expf(-gd));
  const float a  = prelu_a[0];

  // ---- gated residual + row norm ----
  f4 o0 = fma4s(gt, prelu4(acc0, a), hr0);
  f4 o1 = fma4s(gt, prelu4(acc1, a), hr1);
  f4 o2 = fma4s(gt, prelu4(acc2, a), hr2);
  f4 o3 = fma4s(gt, prelu4(acc3, a), hr3);

  float ss = o0.x * o0.x + o0.y * o0.y + o0.z * o0.z + o0.w * o0.w;
  ss = fmaf(o1.x, o1.x, ss); ss = fmaf(o1.y, o1.y, ss);
  ss = fmaf(o1.z, o1.z, ss); ss = fmaf(o1.w, o1.w, ss);
  ss = fmaf(o2.x, o2.x, ss); ss = fmaf(o2.y, o2.y, ss);
  ss = fmaf(o2.z, o2.z, ss); ss = fmaf(o2.w, o2.w, ss);
  ss = fmaf(o3.x, o3.x, ss); ss = fmaf(o3.y, o3.y, ss);
  ss = fmaf(o3.z, o3.z, ss); ss = fmaf(o3.w, o3.w, ss);
  ss += __shfl_xor(ss, 16);
  ss += __shfl_xor(ss, 32);
  const float rn = rsqrtf(ss);

  if (hasT && r < nrem) {
    float* __restrict__ orow = out + (size_t)(j0 + r) * D + g * 4;
    *reinterpret_cast<f4*>(orow +  0) = o0 * rn;
    *reinterpret_cast<f4*>(orow + 16) = o1 * rn;
    *reinterpret_cast<f4*>(orow + 32) = o2 * rn;
    *reinterpret_cast<f4*>(orow + 48) = o3 * rn;
  }
}

extern "C" void kernel_launch(void* const* d_in, const int* in_sizes, int n_in,
                              void* d_out, int out_size, void* d_ws, size_t ws_size,
                              hipStream_t stream) {
  const float* s       = (const float*)d_in[0];
  const float* h       = (const float*)d_in[1];
  const float* keys    = (const float*)d_in[2];
  const float* U       = (const float*)d_in[3];
  const float* V       = (const float*)d_in[4];
  const float* W       = (const float*)d_in[5];
  const float* bias    = (const float*)d_in[6];
  const float* prelu_a = (const float*)d_in[7];
  float* out = (float*)d_out;

  const int nblocks = in_sizes[1] / D;
  const int ntiles  = (nblocks + ROWS - 1) / ROWS;
  const int grid    = (ntiles + 1) / 2;
  dmc_fused<<<grid, TPB, 0, stream>>>(h, keys, s, U, V, W, bias, prelu_a, out,
                                      nblocks, ntiles);
}

// Round 18
// 102.017 us; speedup vs baseline: 1.1704x; 1.0473x over previous
//
#include <hip/hip_runtime.h>

#define D 64
#define ROWS 64
#define TPB 256

typedef float f4 __attribute__((ext_vector_type(4)));
typedef short s8 __attribute__((ext_vector_type(8)));

static __device__ __forceinline__ unsigned short f2bf(float x) {
  union { float f; unsigned u; } v; v.f = x;
  return (unsigned short)((v.u + 0x7FFFu + ((v.u >> 16) & 1u)) >> 16);
}

static __device__ __forceinline__ s8 pack8(f4 a, f4 b) {
  s8 r;
  r[0] = (short)f2bf(a.x); r[1] = (short)f2bf(a.y);
  r[2] = (short)f2bf(a.z); r[3] = (short)f2bf(a.w);
  r[4] = (short)f2bf(b.x); r[5] = (short)f2bf(b.y);
  r[6] = (short)f2bf(b.z); r[7] = (short)f2bf(b.w);
  return r;
}

static __device__ __forceinline__ f4 fma4s(float a, f4 b, f4 c) {
  f4 r;
  r.x = fmaf(a, b.x, c.x);
  r.y = fmaf(a, b.y, c.y);
  r.z = fmaf(a, b.z, c.z);
  r.w = fmaf(a, b.w, c.w);
  return r;
}

static __device__ __forceinline__ f4 prelu4(f4 p, float a) {
  f4 r;
  r.x = p.x >= 0.0f ? p.x : a * p.x;
  r.y = p.y >= 0.0f ? p.y : a * p.y;
  r.z = p.z >= 0.0f ? p.z : a * p.z;
  r.w = p.w >= 0.0f ? p.w : a * p.w;
  return r;
}

static __device__ __forceinline__ float dot4(f4 x, f4 y, f4 z, float acc) {
  acc = fmaf(x.x + y.x, z.x, acc);
  acc = fmaf(x.y + y.y, z.y, acc);
  acc = fmaf(x.z + y.z, z.z, acc);
  acc = fmaf(x.w + y.w, z.w, acc);
  return acc;
}

// Issue a 16B global load as raw asm: 12 distinct dest registers, compiler
// cannot coalesce/serialize the bundle (R15/R17: scheduler kept collapsing
// the burst to ~4-deep, VGPR 60/40). Static offset immediates; 3 base addrs.
#define GLOAD(dst, ptr, OFF) \
  asm volatile("global_load_dwordx4 %0, %1, off offset:" #OFF \
               : "=v"(dst) : "v"(ptr))

// R18 = R15 with the 12 h/k loads as inline-asm global_load_dwordx4.
// All 12 issue back-to-back and stay outstanding through U/V/cc staging
// (vmcnt retires in order, so staging's own waits also cover ours); one
// s_waitcnt vmcnt(0) + sched_barrier(0) after the block barrier (rule #18:
// VALU consumers would otherwise hoist above an asm waitcnt), then consume.
// Per-block load phase: ~3 serialized latency windows -> 1.
__global__ __launch_bounds__(TPB, 4) void dmc_fused(
    const float* __restrict__ h,
    const float* __restrict__ keys,
    const float* __restrict__ s,
    const float* __restrict__ U,
    const float* __restrict__ V,
    const float* __restrict__ W,
    const float* __restrict__ bias,
    const float* __restrict__ prelu_a,
    float* __restrict__ out,
    const int nblocks) {
  __shared__ __align__(16) unsigned short Ub[D * D];  // 8KB bf16, swizzled
  __shared__ __align__(16) unsigned short Vb[D * D];  // 8KB
  __shared__ __align__(16) float cc[D];

  const int tid  = threadIdx.x;
  const int lane = tid & 63;
  const int wv   = tid >> 6;            // 0..3 = batch row-block
  const int g    = lane >> 4;           // 0..3
  const int rl   = lane & 15;           // MFMA n (batch row) / m (U row)
  const int r    = wv * 16 + rl;        // batch row within tile
  const int j0   = blockIdx.x * ROWS;
  const int nrem = nblocks - j0;
  const int rc   = (r < nrem) ? r : (nrem - 1);

  // ---- 1) issue ALL 12 loads via asm (12 distinct dests, 3 bases) ----
  const float* hbase = h + (size_t)(j0 + rc) * D;
  const float* kbase = keys + (size_t)(j0 + rc) * D;
  const f4* hB = reinterpret_cast<const f4*>(hbase) + 2 * g;  // B-frag base
  const f4* hR = reinterpret_cast<const f4*>(hbase) + g;      // residual base
  const f4* kB = reinterpret_cast<const f4*>(kbase) + 2 * g;

  f4 ph0a, ph0b, ph1a, ph1b, pk0a, pk0b, pk1a, pk1b, hr0, hr1, hr2, hr3;
  GLOAD(ph0a, hB, 0);
  GLOAD(ph0b, hB, 16);
  GLOAD(ph1a, hB, 128);
  GLOAD(ph1b, hB, 144);
  GLOAD(pk0a, kB, 0);
  GLOAD(pk0b, kB, 16);
  GLOAD(pk1a, kB, 128);
  GLOAD(pk1b, kB, 144);
  GLOAD(hr0, hR, 0);
  GLOAD(hr1, hR, 64);
  GLOAD(hr2, hR, 128);
  GLOAD(hr3, hR, 192);
  // Pin: staging below must not be hoisted above the asm loads.
  __builtin_amdgcn_sched_barrier(0);

  // ---- 2) stage U, V -> bf16 LDS (overlaps the 12 in-flight loads) ----
  const f4* __restrict__ Ug = reinterpret_cast<const f4*>(U);
  const f4* __restrict__ Vg = reinterpret_cast<const f4*>(V);
  s8* __restrict__ Ub8w = reinterpret_cast<s8*>(Ub);
  s8* __restrict__ Vb8w = reinterpret_cast<s8*>(Vb);
  #pragma unroll
  for (int t = 0; t < 2; ++t) {
    const int m  = tid + TPB * t;       // 0..511 chunk id
    const int c  = m >> 3;
    const int sl = m & 7;
    Ub8w[c * 8 + (sl ^ (c & 7))] = pack8(Ug[c * 16 + sl * 2], Ug[c * 16 + sl * 2 + 1]);
    Vb8w[c * 8 + (sl ^ (c & 7))] = pack8(Vg[c * 16 + sl * 2], Vg[c * 16 + sl * 2 + 1]);
  }

  // ---- cc[c] = bias[c] + W[c,:] @ s ----
  if (tid < D) {
    const f4* __restrict__ wr = reinterpret_cast<const f4*>(W + tid * D);
    const f4* __restrict__ sr = reinterpret_cast<const f4*>(s);
    float acc = bias[tid];
    #pragma unroll
    for (int q = 0; q < 16; ++q) {
      const f4 wq = wr[q];
      const f4 sq = sr[q];
      acc = fmaf(wq.x, sq.x, acc);
      acc = fmaf(wq.y, sq.y, acc);
      acc = fmaf(wq.z, sq.z, acc);
      acc = fmaf(wq.w, sq.w, acc);
    }
    cc[tid] = acc;
  }
  __syncthreads();

  // ---- 3) drain our asm loads, then consume ----
  asm volatile("s_waitcnt vmcnt(0)" ::: "memory");
  __builtin_amdgcn_sched_barrier(0);

  const f4* __restrict__ sg4 = reinterpret_cast<const f4*>(s);
  float gd = dot4(ph0a, pk0a, sg4[2 * g], 0.0f);
  gd = dot4(ph0b, pk0b, sg4[2 * g + 1], gd);
  gd = dot4(ph1a, pk1a, sg4[8 + 2 * g], gd);
  gd = dot4(ph1b, pk1b, sg4[8 + 2 * g + 1], gd);
  const s8 bh0 = pack8(ph0a, ph0b);
  const s8 bh1 = pack8(ph1a, ph1b);
  const s8 bk0 = pack8(pk0a, pk0b);
  const s8 bk1 = pack8(pk1a, pk1b);

  // ---- accumulators from cc ----
  const f4* __restrict__ cc4 = reinterpret_cast<const f4*>(cc);
  f4 acc0 = cc4[0 + g];
  f4 acc1 = cc4[4 + g];
  f4 acc2 = cc4[8 + g];
  f4 acc3 = cc4[12 + g];

  // ---- MFMA: K=64 as 2 slices of 32 (A-frags from swizzled LDS) ----
  const s8* __restrict__ Ub8 = reinterpret_cast<const s8*>(Ub);
  const s8* __restrict__ Vb8 = reinterpret_cast<const s8*>(Vb);
  #pragma unroll
  for (int ks = 0; ks < 2; ++ks) {
    const int asl = ks * 4 + g;
    const s8 bh = (ks == 0) ? bh0 : bh1;
    const s8 bk = (ks == 0) ? bk0 : bk1;
    const int c0i = 0 * 16 + rl, c1i = 1 * 16 + rl;
    const int c2i = 2 * 16 + rl, c3i = 3 * 16 + rl;
    const s8 au0 = Ub8[c0i * 8 + (asl ^ (c0i & 7))];
    const s8 au1 = Ub8[c1i * 8 + (asl ^ (c1i & 7))];
    const s8 au2 = Ub8[c2i * 8 + (asl ^ (c2i & 7))];
    const s8 au3 = Ub8[c3i * 8 + (asl ^ (c3i & 7))];
    const s8 av0 = Vb8[c0i * 8 + (asl ^ (c0i & 7))];
    const s8 av1 = Vb8[c1i * 8 + (asl ^ (c1i & 7))];
    const s8 av2 = Vb8[c2i * 8 + (asl ^ (c2i & 7))];
    const s8 av3 = Vb8[c3i * 8 + (asl ^ (c3i & 7))];
    acc0 = __builtin_amdgcn_mfma_f32_16x16x32_bf16(au0, bh, acc0, 0, 0, 0);
    acc1 = __builtin_amdgcn_mfma_f32_16x16x32_bf16(au1, bh, acc1, 0, 0, 0);
    acc2 = __builtin_amdgcn_mfma_f32_16x16x32_bf16(au2, bh, acc2, 0, 0, 0);
    acc3 = __builtin_amdgcn_mfma_f32_16x16x32_bf16(au3, bh, acc3, 0, 0, 0);
    acc0 = __builtin_amdgcn_mfma_f32_16x16x32_bf16(av0, bk, acc0, 0, 0, 0);
    acc1 = __builtin_amdgcn_mfma_f32_16x16x32_bf16(av1, bk, acc1, 0, 0, 0);
    acc2 = __builtin_amdgcn_mfma_f32_16x16x32_bf16(av2, bk, acc2, 0, 0, 0);
    acc3 = __builtin_amdgcn_mfma_f32_16x16x32_bf16(av3, bk, acc3, 0, 0, 0);
  }

  // ---- gate reduce (lanes of equal rl hold disjoint k-ranges) ----
  gd += __shfl_xor(gd, 16);
  gd += __shfl_xor(gd, 32);
  const float gt = 1.0f / (1.0f + __expf(-gd));
  const float a  = prelu_a[0];

  // ---- gated residual + row norm ----
  f4 o0 = fma4s(gt, prelu4(acc0, a), hr0);
  f4 o1 = fma4s(gt, prelu4(acc1, a), hr1);
  f4 o2 = fma4s(gt, prelu4(acc2, a), hr2);
  f4 o3 = fma4s(gt, prelu4(acc3, a), hr3);

  float ss = o0.x * o0.x + o0.y * o0.y + o0.z * o0.z + o0.w * o0.w;
  ss = fmaf(o1.x, o1.x, ss); ss = fmaf(o1.y, o1.y, ss);
  ss = fmaf(o1.z, o1.z, ss); ss = fmaf(o1.w, o1.w, ss);
  ss = fmaf(o2.x, o2.x, ss); ss = fmaf(o2.y, o2.y, ss);
  ss = fmaf(o2.z, o2.z, ss); ss = fmaf(o2.w, o2.w, ss);
  ss = fmaf(o3.x, o3.x, ss); ss = fmaf(o3.y, o3.y, ss);
  ss = fmaf(o3.z, o3.z, ss); ss = fmaf(o3.w, o3.w, ss);
  ss += __shfl_xor(ss, 16);
  ss += __shfl_xor(ss, 32);
  const float rn = rsqrtf(ss);

  if (r < nrem) {
    float* __restrict__ orow = out + (size_t)(j0 + r) * D + g * 4;
    *reinterpret_cast<f4*>(orow +  0) = o0 * rn;
    *reinterpret_cast<f4*>(orow + 16) = o1 * rn;
    *reinterpret_cast<f4*>(orow + 32) = o2 * rn;
    *reinterpret_cast<f4*>(orow + 48) = o3 * rn;
  }
}

extern "C" void kernel_launch(void* const* d_in, const int* in_sizes, int n_in,
                              void* d_out, int out_size, void* d_ws, size_t ws_size,
                              hipStream_t stream) {
  const float* s       = (const float*)d_in[0];
  const float* h       = (const float*)d_in[1];
  const float* keys    = (const float*)d_in[2];
  const float* U       = (const float*)d_in[3];
  const float* V       = (const float*)d_in[4];
  const float* W       = (const float*)d_in[5];
  const float* bias    = (const float*)d_in[6];
  const float* prelu_a = (const float*)d_in[7];
  float* out = (float*)d_out;

  const int nblocks = in_sizes[1] / D;
  const int grid = (nblocks + ROWS - 1) / ROWS;
  dmc_fused<<<grid, TPB, 0, stream>>>(h, keys, s, U, V, W, bias, prelu_a, out,
                                      nblocks);
}

// Round 19
// 91.711 us; speedup vs baseline: 1.3019x; 1.1124x over previous
//
#include <hip/hip_runtime.h>

#define D 64
#define ROWS 64
#define TPB 256

typedef float f4 __attribute__((ext_vector_type(4)));
typedef short s8 __attribute__((ext_vector_type(8)));

static __device__ __forceinline__ unsigned short f2bf(float x) {
  union { float f; unsigned u; } v; v.f = x;
  return (unsigned short)((v.u + 0x7FFFu + ((v.u >> 16) & 1u)) >> 16);
}

static __device__ __forceinline__ s8 pack8(f4 a, f4 b) {
  s8 r;
  r[0] = (short)f2bf(a.x); r[1] = (short)f2bf(a.y);
  r[2] = (short)f2bf(a.z); r[3] = (short)f2bf(a.w);
  r[4] = (short)f2bf(b.x); r[5] = (short)f2bf(b.y);
  r[6] = (short)f2bf(b.z); r[7] = (short)f2bf(b.w);
  return r;
}

static __device__ __forceinline__ f4 fma4s(float a, f4 b, f4 c) {
  f4 r;
  r.x = fmaf(a, b.x, c.x);
  r.y = fmaf(a, b.y, c.y);
  r.z = fmaf(a, b.z, c.z);
  r.w = fmaf(a, b.w, c.w);
  return r;
}

static __device__ __forceinline__ f4 prelu4(f4 p, float a) {
  f4 r;
  r.x = p.x >= 0.0f ? p.x : a * p.x;
  r.y = p.y >= 0.0f ? p.y : a * p.y;
  r.z = p.z >= 0.0f ? p.z : a * p.z;
  r.w = p.w >= 0.0f ? p.w : a * p.w;
  return r;
}

static __device__ __forceinline__ float dot4(f4 x, f4 y, f4 z, float acc) {
  acc = fmaf(x.x + y.x, z.x, acc);
  acc = fmaf(x.y + y.y, z.y, acc);
  acc = fmaf(x.z + y.z, z.z, acc);
  acc = fmaf(x.w + y.w, z.w, acc);
  return acc;
}

static __device__ __forceinline__ f4 shfl4(f4 v, int src) {
  f4 r;
  r.x = __shfl(v.x, src);
  r.y = __shfl(v.y, src);
  r.z = __shfl(v.z, src);
  r.w = __shfl(v.w, src);
  return r;
}

// Raw asm 16B load with distinct dest (compiler cannot coalesce/serialize).
#define GLOAD(dst, ptr, OFF) \
  asm volatile("global_load_dwordx4 %0, %1, off offset:" #OFF \
               : "=v"(dst) : "v"(ptr))

// R19 = R18 minus the 4 hr loads: requests/wave 12->8, bytes unchanged
// (hr lines were duplicates of B-frag lines). hr derived in-register via
// the R13-verified quad-shuffle identity: chunk 4N+g of row rl lives in
// lane srcA=(g>>1)*16+rl (N even-half) / srcB=srcA+32 (N odd-half),
// register pair ph0*/ph1*, select by g&1. Clean A/B on TA request count.
__global__ __launch_bounds__(TPB, 4) void dmc_fused(
    const float* __restrict__ h,
    const float* __restrict__ keys,
    const float* __restrict__ s,
    const float* __restrict__ U,
    const float* __restrict__ V,
    const float* __restrict__ W,
    const float* __restrict__ bias,
    const float* __restrict__ prelu_a,
    float* __restrict__ out,
    const int nblocks) {
  __shared__ __align__(16) unsigned short Ub[D * D];  // 8KB bf16, swizzled
  __shared__ __align__(16) unsigned short Vb[D * D];  // 8KB
  __shared__ __align__(16) float cc[D];

  const int tid  = threadIdx.x;
  const int lane = tid & 63;
  const int wv   = tid >> 6;            // 0..3 = batch row-block
  const int g    = lane >> 4;           // 0..3
  const int rl   = lane & 15;           // MFMA n (batch row) / m (U row)
  const int r    = wv * 16 + rl;        // batch row within tile
  const int j0   = blockIdx.x * ROWS;
  const int nrem = nblocks - j0;
  const int rc   = (r < nrem) ? r : (nrem - 1);

  // ---- 1) issue the 8 B-frag loads via asm (8 distinct dests, 2 bases) ----
  const float* hbase = h + (size_t)(j0 + rc) * D;
  const float* kbase = keys + (size_t)(j0 + rc) * D;
  const f4* hB = reinterpret_cast<const f4*>(hbase) + 2 * g;
  const f4* kB = reinterpret_cast<const f4*>(kbase) + 2 * g;

  f4 ph0a, ph0b, ph1a, ph1b, pk0a, pk0b, pk1a, pk1b;
  GLOAD(ph0a, hB, 0);
  GLOAD(ph0b, hB, 16);
  GLOAD(ph1a, hB, 128);
  GLOAD(ph1b, hB, 144);
  GLOAD(pk0a, kB, 0);
  GLOAD(pk0b, kB, 16);
  GLOAD(pk1a, kB, 128);
  GLOAD(pk1b, kB, 144);
  // Pin: staging below must not be hoisted above the asm loads.
  __builtin_amdgcn_sched_barrier(0);

  // ---- 2) stage U, V -> bf16 LDS (overlaps the 8 in-flight loads) ----
  const f4* __restrict__ Ug = reinterpret_cast<const f4*>(U);
  const f4* __restrict__ Vg = reinterpret_cast<const f4*>(V);
  s8* __restrict__ Ub8w = reinterpret_cast<s8*>(Ub);
  s8* __restrict__ Vb8w = reinterpret_cast<s8*>(Vb);
  #pragma unroll
  for (int t = 0; t < 2; ++t) {
    const int m  = tid + TPB * t;       // 0..511 chunk id
    const int c  = m >> 3;
    const int sl = m & 7;
    Ub8w[c * 8 + (sl ^ (c & 7))] = pack8(Ug[c * 16 + sl * 2], Ug[c * 16 + sl * 2 + 1]);
    Vb8w[c * 8 + (sl ^ (c & 7))] = pack8(Vg[c * 16 + sl * 2], Vg[c * 16 + sl * 2 + 1]);
  }

  // ---- cc[c] = bias[c] + W[c,:] @ s ----
  if (tid < D) {
    const f4* __restrict__ wr = reinterpret_cast<const f4*>(W + tid * D);
    const f4* __restrict__ sr = reinterpret_cast<const f4*>(s);
    float acc = bias[tid];
    #pragma unroll
    for (int q = 0; q < 16; ++q) {
      const f4 wq = wr[q];
      const f4 sq = sr[q];
      acc = fmaf(wq.x, sq.x, acc);
      acc = fmaf(wq.y, sq.y, acc);
      acc = fmaf(wq.z, sq.z, acc);
      acc = fmaf(wq.w, sq.w, acc);
    }
    cc[tid] = acc;
  }
  __syncthreads();

  // ---- 3) drain our asm loads, then consume ----
  asm volatile("s_waitcnt vmcnt(0)" ::: "memory");
  __builtin_amdgcn_sched_barrier(0);

  const f4* __restrict__ sg4 = reinterpret_cast<const f4*>(s);
  float gd = dot4(ph0a, pk0a, sg4[2 * g], 0.0f);
  gd = dot4(ph0b, pk0b, sg4[2 * g + 1], gd);
  gd = dot4(ph1a, pk1a, sg4[8 + 2 * g], gd);
  gd = dot4(ph1b, pk1b, sg4[8 + 2 * g + 1], gd);
  const s8 bh0 = pack8(ph0a, ph0b);
  const s8 bh1 = pack8(ph1a, ph1b);
  const s8 bk0 = pack8(pk0a, pk0b);
  const s8 bk1 = pack8(pk1a, pk1b);

  // hr in D-frag layout via quad shuffles (no global reads; R13-verified)
  const int srcA = ((g >> 1) << 4) + rl;
  const int srcB = srcA + 32;
  const int odd  = g & 1;
  const f4 A0 = shfl4(ph0a, srcA), B0 = shfl4(ph0b, srcA);
  const f4 A1 = shfl4(ph0a, srcB), B1 = shfl4(ph0b, srcB);
  const f4 A2 = shfl4(ph1a, srcA), B2 = shfl4(ph1b, srcA);
  const f4 A3 = shfl4(ph1a, srcB), B3 = shfl4(ph1b, srcB);
  const f4 hr0 = odd ? B0 : A0;
  const f4 hr1 = odd ? B1 : A1;
  const f4 hr2 = odd ? B2 : A2;
  const f4 hr3 = odd ? B3 : A3;

  // ---- accumulators from cc ----
  const f4* __restrict__ cc4 = reinterpret_cast<const f4*>(cc);
  f4 acc0 = cc4[0 + g];
  f4 acc1 = cc4[4 + g];
  f4 acc2 = cc4[8 + g];
  f4 acc3 = cc4[12 + g];

  // ---- MFMA: K=64 as 2 slices of 32 (A-frags from swizzled LDS) ----
  const s8* __restrict__ Ub8 = reinterpret_cast<const s8*>(Ub);
  const s8* __restrict__ Vb8 = reinterpret_cast<const s8*>(Vb);
  #pragma unroll
  for (int ks = 0; ks < 2; ++ks) {
    const int asl = ks * 4 + g;
    const s8 bh = (ks == 0) ? bh0 : bh1;
    const s8 bk = (ks == 0) ? bk0 : bk1;
    const int c0i = 0 * 16 + rl, c1i = 1 * 16 + rl;
    const int c2i = 2 * 16 + rl, c3i = 3 * 16 + rl;
    const s8 au0 = Ub8[c0i * 8 + (asl ^ (c0i & 7))];
    const s8 au1 = Ub8[c1i * 8 + (asl ^ (c1i & 7))];
    const s8 au2 = Ub8[c2i * 8 + (asl ^ (c2i & 7))];
    const s8 au3 = Ub8[c3i * 8 + (asl ^ (c3i & 7))];
    const s8 av0 = Vb8[c0i * 8 + (asl ^ (c0i & 7))];
    const s8 av1 = Vb8[c1i * 8 + (asl ^ (c1i & 7))];
    const s8 av2 = Vb8[c2i * 8 + (asl ^ (c2i & 7))];
    const s8 av3 = Vb8[c3i * 8 + (asl ^ (c3i & 7))];
    acc0 = __builtin_amdgcn_mfma_f32_16x16x32_bf16(au0, bh, acc0, 0, 0, 0);
    acc1 = __builtin_amdgcn_mfma_f32_16x16x32_bf16(au1, bh, acc1, 0, 0, 0);
    acc2 = __builtin_amdgcn_mfma_f32_16x16x32_bf16(au2, bh, acc2, 0, 0, 0);
    acc3 = __builtin_amdgcn_mfma_f32_16x16x32_bf16(au3, bh, acc3, 0, 0, 0);
    acc0 = __builtin_amdgcn_mfma_f32_16x16x32_bf16(av0, bk, acc0, 0, 0, 0);
    acc1 = __builtin_amdgcn_mfma_f32_16x16x32_bf16(av1, bk, acc1, 0, 0, 0);
    acc2 = __builtin_amdgcn_mfma_f32_16x16x32_bf16(av2, bk, acc2, 0, 0, 0);
    acc3 = __builtin_amdgcn_mfma_f32_16x16x32_bf16(av3, bk, acc3, 0, 0, 0);
  }

  // ---- gate reduce (lanes of equal rl hold disjoint k-ranges) ----
  gd += __shfl_xor(gd, 16);
  gd += __shfl_xor(gd, 32);
  const float gt = 1.0f / (1.0f + __expf(-gd));
  const float a  = prelu_a[0];

  // ---- gated residual + row norm ----
  f4 o0 = fma4s(gt, prelu4(acc0, a), hr0);
  f4 o1 = fma4s(gt, prelu4(acc1, a), hr1);
  f4 o2 = fma4s(gt, prelu4(acc2, a), hr2);
  f4 o3 = fma4s(gt, prelu4(acc3, a), hr3);

  float ss = o0.x * o0.x + o0.y * o0.y + o0.z * o0.z + o0.w * o0.w;
  ss = fmaf(o1.x, o1.x, ss); ss = fmaf(o1.y, o1.y, ss);
  ss = fmaf(o1.z, o1.z, ss); ss = fmaf(o1.w, o1.w, ss);
  ss = fmaf(o2.x, o2.x, ss); ss = fmaf(o2.y, o2.y, ss);
  ss = fmaf(o2.z, o2.z, ss); ss = fmaf(o2.w, o2.w, ss);
  ss = fmaf(o3.x, o3.x, ss); ss = fmaf(o3.y, o3.y, ss);
  ss = fmaf(o3.z, o3.z, ss); ss = fmaf(o3.w, o3.w, ss);
  ss += __shfl_xor(ss, 16);
  ss += __shfl_xor(ss, 32);
  const float rn = rsqrtf(ss);

  if (r < nrem) {
    float* __restrict__ orow = out + (size_t)(j0 + r) * D + g * 4;
    *reinterpret_cast<f4*>(orow +  0) = o0 * rn;
    *reinterpret_cast<f4*>(orow + 16) = o1 * rn;
    *reinterpret_cast<f4*>(orow + 32) = o2 * rn;
    *reinterpret_cast<f4*>(orow + 48) = o3 * rn;
  }
}

extern "C" void kernel_launch(void* const* d_in, const int* in_sizes, int n_in,
                              void* d_out, int out_size, void* d_ws, size_t ws_size,
                              hipStream_t stream) {
  const float* s       = (const float*)d_in[0];
  const float* h       = (const float*)d_in[1];
  const float* keys    = (const float*)d_in[2];
  const float* U       = (const float*)d_in[3];
  const float* V       = (const float*)d_in[4];
  const float* W       = (const float*)d_in[5];
  const float* bias    = (const float*)d_in[6];
  const float* prelu_a = (const float*)d_in[7];
  float* out = (float*)d_out;

  const int nblocks = in_sizes[1] / D;
  const int grid = (nblocks + ROWS - 1) / ROWS;
  dmc_fused<<<grid, TPB, 0, stream>>>(h, keys, s, U, V, W, bias, prelu_a, out,
                                      nblocks);
}